// Round 10
// baseline (17111.635 us; speedup 1.0000x reference)
//
#include <hip/hip_runtime.h>
#include <hip/hip_bf16.h>
#include <cstdint>

#define SENTW 0x7F7F7F7Fu                    // float ~3.39e38; |h|<1 never produces it
#define SENT64 0x7F7F7F7F7F7F7F7FULL

// fast activations: v_exp_f32 (2^x) + v_rcp_f32, ~1-2 ulp each
__device__ __forceinline__ float fexp(float x){
  return __builtin_amdgcn_exp2f(x * 1.44269504088896341f);
}
__device__ __forceinline__ float sigf(float x){
  return __builtin_amdgcn_rcpf(1.f + fexp(-x));
}
__device__ __forceinline__ float tanh_fast(float x){
  return 1.f - 2.f*__builtin_amdgcn_rcpf(fexp(2.f*x) + 1.f);
}

// ---------------- embedding ----------------
__global__ __launch_bounds__(256) void k_embed(
    const int* __restrict__ x, const int* __restrict__ xp,
    const float* __restrict__ we, const float* __restrict__ pe,
    float* __restrict__ X)
{
  const int s = blockIdx.x, t = threadIdx.x;
  float4* xr = (float4*)(X + (size_t)s*1024);
  if (t < 224){
    const float4* wr = (const float4*)(we + (size_t)x[s]*896);
    xr[t] = wr[t];
  } else {
    const float4* pr = (const float4*)(pe + (size_t)xp[s]*128);
    xr[t] = pr[t-224];
  }
}

// ---------------- fp32 GEMM: C = A * B^T + bias + (*cadd) ----------------
__global__ __launch_bounds__(256,2) void k_gemm_abT(
    const float* __restrict__ A, const float* __restrict__ B, float* __restrict__ C,
    int M, int N, int K,
    const float* __restrict__ bias, const float* __restrict__ cadd)
{
  __shared__ float As[16][132];
  __shared__ float Bs[16][132];
  const int tid = threadIdx.x;
  const int m0 = blockIdx.y*128, n0 = blockIdx.x*128;
  const int r  = tid>>1, cq = tid&1;
  const int ty = tid>>4, tx = tid&15;

  float acc[8][8];
  #pragma unroll
  for (int i=0;i<8;i++)
    #pragma unroll
    for (int j=0;j<8;j++) acc[i][j]=0.f;

  for (int k0=0;k0<K;k0+=16){
    const float* ap = A + (size_t)(m0+r)*K + k0 + cq*8;
    const float* bp = B + (size_t)(n0+r)*K + k0 + cq*8;
    float4 a0 = *(const float4*)ap;
    float4 a1 = *(const float4*)(ap+4);
    float4 b0 = *(const float4*)bp;
    float4 b1 = *(const float4*)(bp+4);
    __syncthreads();
    As[cq*8+0][r]=a0.x; As[cq*8+1][r]=a0.y; As[cq*8+2][r]=a0.z; As[cq*8+3][r]=a0.w;
    As[cq*8+4][r]=a1.x; As[cq*8+5][r]=a1.y; As[cq*8+6][r]=a1.z; As[cq*8+7][r]=a1.w;
    Bs[cq*8+0][r]=b0.x; Bs[cq*8+1][r]=b0.y; Bs[cq*8+2][r]=b0.z; Bs[cq*8+3][r]=b0.w;
    Bs[cq*8+4][r]=b1.x; Bs[cq*8+5][r]=b1.y; Bs[cq*8+6][r]=b1.z; Bs[cq*8+7][r]=b1.w;
    __syncthreads();
    #pragma unroll
    for (int k=0;k<16;k++){
      float4 av0 = *(const float4*)&As[k][ty*8];
      float4 av1 = *(const float4*)&As[k][ty*8+4];
      float4 bv0 = *(const float4*)&Bs[k][tx*8];
      float4 bv1 = *(const float4*)&Bs[k][tx*8+4];
      float a[8]={av0.x,av0.y,av0.z,av0.w,av1.x,av1.y,av1.z,av1.w};
      float b[8]={bv0.x,bv0.y,bv0.z,bv0.w,bv1.x,bv1.y,bv1.z,bv1.w};
      #pragma unroll
      for (int i=0;i<8;i++)
        #pragma unroll
        for (int j=0;j<8;j++)
          acc[i][j] = fmaf(a[i],b[j],acc[i][j]);
    }
  }

  float cb = cadd ? *cadd : 0.f;
  float bv[8];
  if (bias){
    float4 t0 = *(const float4*)&bias[n0+tx*8];
    float4 t1 = *(const float4*)&bias[n0+tx*8+4];
    bv[0]=t0.x; bv[1]=t0.y; bv[2]=t0.z; bv[3]=t0.w;
    bv[4]=t1.x; bv[5]=t1.y; bv[6]=t1.z; bv[7]=t1.w;
  } else {
    #pragma unroll
    for (int j=0;j<8;j++) bv[j]=0.f;
  }
  #pragma unroll
  for (int i=0;i<8;i++){
    float* cp = C + (size_t)(m0+ty*8+i)*N + n0+tx*8;
    float4 o0, o1;
    o0.x=acc[i][0]+bv[0]+cb; o0.y=acc[i][1]+bv[1]+cb;
    o0.z=acc[i][2]+bv[2]+cb; o0.w=acc[i][3]+bv[3]+cb;
    o1.x=acc[i][4]+bv[4]+cb; o1.y=acc[i][5]+bv[5]+cb;
    o1.z=acc[i][6]+bv[6]+cb; o1.w=acc[i][7]+bv[7]+cb;
    *(float4*)cp = o0; *(float4*)(cp+4) = o1;
  }
}

// ---- merged head/dep GEMM ----
__global__ __launch_bounds__(256,2) void k_gemm_hd(
    const float* __restrict__ A,
    const float* __restrict__ Wh, const float* __restrict__ bh, float* __restrict__ Chead,
    const float* __restrict__ Wd, const float* __restrict__ bd, float* __restrict__ Cdep)
{
  __shared__ float As[16][132];
  __shared__ float Bs[16][132];
  const int tid = threadIdx.x;
  const int m0 = blockIdx.y*128;
  const int half = blockIdx.x >> 3;
  const int n0 = (blockIdx.x & 7)*128;
  const float* B    = half ? Wd : Wh;
  const float* bias = half ? bd : bh;
  float*       C    = half ? Cdep : Chead;
  const int r  = tid>>1, cq = tid&1;
  const int ty = tid>>4, tx = tid&15;

  float acc[8][8];
  #pragma unroll
  for (int i=0;i<8;i++)
    #pragma unroll
    for (int j=0;j<8;j++) acc[i][j]=0.f;

  for (int k0=0;k0<1024;k0+=16){
    const float* ap = A + (size_t)(m0+r)*1024 + k0 + cq*8;
    const float* bp = B + (size_t)(n0+r)*1024 + k0 + cq*8;
    float4 a0 = *(const float4*)ap;
    float4 a1 = *(const float4*)(ap+4);
    float4 b0 = *(const float4*)bp;
    float4 b1 = *(const float4*)(bp+4);
    __syncthreads();
    As[cq*8+0][r]=a0.x; As[cq*8+1][r]=a0.y; As[cq*8+2][r]=a0.z; As[cq*8+3][r]=a0.w;
    As[cq*8+4][r]=a1.x; As[cq*8+5][r]=a1.y; As[cq*8+6][r]=a1.z; As[cq*8+7][r]=a1.w;
    Bs[cq*8+0][r]=b0.x; Bs[cq*8+1][r]=b0.y; Bs[cq*8+2][r]=b0.z; Bs[cq*8+3][r]=b0.w;
    Bs[cq*8+4][r]=b1.x; Bs[cq*8+5][r]=b1.y; Bs[cq*8+6][r]=b1.z; Bs[cq*8+7][r]=b1.w;
    __syncthreads();
    #pragma unroll
    for (int k=0;k<16;k++){
      float4 av0 = *(const float4*)&As[k][ty*8];
      float4 av1 = *(const float4*)&As[k][ty*8+4];
      float4 bv0 = *(const float4*)&Bs[k][tx*8];
      float4 bv1 = *(const float4*)&Bs[k][tx*8+4];
      float a[8]={av0.x,av0.y,av0.z,av0.w,av1.x,av1.y,av1.z,av1.w};
      float b[8]={bv0.x,bv0.y,bv0.z,bv0.w,bv1.x,bv1.y,bv1.z,bv1.w};
      #pragma unroll
      for (int i=0;i<8;i++)
        #pragma unroll
        for (int j=0;j<8;j++)
          acc[i][j] = fmaf(a[i],b[j],acc[i][j]);
    }
  }

  float4 t0 = *(const float4*)&bias[n0+tx*8];
  float4 t1 = *(const float4*)&bias[n0+tx*8+4];
  float bv[8] = {t0.x,t0.y,t0.z,t0.w,t1.x,t1.y,t1.z,t1.w};
  #pragma unroll
  for (int i=0;i<8;i++){
    float* cp = C + (size_t)(m0+ty*8+i)*1024 + n0+tx*8;
    float4 o0, o1;
    o0.x=acc[i][0]+bv[0]; o0.y=acc[i][1]+bv[1];
    o0.z=acc[i][2]+bv[2]; o0.w=acc[i][3]+bv[3];
    o1.x=acc[i][4]+bv[4]; o1.y=acc[i][5]+bv[5];
    o1.z=acc[i][6]+bv[6]; o1.w=acc[i][7]+bv[7];
    *(float4*)cp = o0; *(float4*)(cp+4) = o1;
  }
}

// ---------------- LSTM scan: private-mailbox exchange ----------------
// 64 WGs x 512 thr (32/dir, 16 units each; weights register-resident).
// NEW (R9): h exchange via per-consumer PRIVATE mailboxes instead of shared
// out[] lines. mb layout: u64 slot index = ((dir*32 + C)*2 + parity)*256 + s,
// where slot s holds h[2s],h[2s+1] (producer WG P=s>>3, wave wv=s&7).
// Producer wave: 32 lanes fan out its 2-unit u64 to all 32 consumers with
// RELEASE stores. Consumer thread tid<256 polls ITS slot (single reader,
// single writer-group per line), then resets it to sentinel for reuse at the
// same parity two steps later.
// Reset-race safety (induction): consumer C's resets (waves 0..3, during
// consume of step t) are ordered before C's RELEASE publishes of step t
// (same-wave vmcnt drain); producer P writes parity(t) slots again only at
// step t+2, after P consumed step t+1, which requires C's t+1 publish, which
// requires C's consume of t => C's resets drained. Same-thread same-address
// program order covers C's own re-poll at t+2.
// out[] is now a plain data store (read only by later kernels) - off the
// critical path; no sentinel memset of out needed.
__global__ __launch_bounds__(512,1) void k_lstm_scan(
    const float* __restrict__ pre,   // [1024][4096]: dir*2048 + gate*512 + unit
    const float* __restrict__ Whh,   // [2][2048][512] (this layer)
    float* __restrict__ out,         // [1024][1024]; fwd 0..511, bwd 512..1023
    unsigned long long* __restrict__ mb) // mailboxes: 2*32*2*256 u64 = 256KB
{
  const int wg  = blockIdx.x;
  const int dir = wg >> 5;
  const int w   = wg & 31;
  const int tid = threadIdx.x;
  const int kc  = tid & 7;          // k-chunk (64 floats)
  const int rl  = tid >> 3;         // local row 0..63
  const int gate= rl & 3;           // i,f,g,o
  const int ul  = rl >> 2;          // local unit 0..15
  const int unit= w*16 + ul;
  const int grow= gate*512 + unit;
  const int wv  = tid >> 6;         // wave 0..7
  const int lane= tid & 63;

  // swizzled LDS: h[i] at slot (i>>6)*68 + (i&63) -> conflict-free b128 reads
  __shared__ float hsh[2][544];
  const int wslot = (tid>>5)*68 + ((2*tid)&63);   // staging slot for h[2*tid] (tid<256)

  float wreg[64];
  {
    const float* wp = Whh + ((size_t)dir*2048 + grow)*512 + kc*64;
    #pragma unroll
    for (int j=0;j<16;j++){
      float4 q = *(const float4*)(wp + 4*j);
      wreg[4*j+0]=q.x; wreg[4*j+1]=q.y; wreg[4*j+2]=q.z; wreg[4*j+3]=q.w;
    }
  }

  const float* prebase = pre + (size_t)dir*2048 + grow;
  unsigned long long* mbc = mb + ((size_t)(dir*32 + w)*2)*256;  // this WG's consumer base
  float c = 0.f;
  const int base = (tid & 32);

  for (int t=0;t<1024;t++){
    const int s = dir ? (1023 - t) : t;

    // prefetch input-projection value (independent of h -> issues before poll)
    float preval = 0.f;
    if (kc==0) preval = prebase[(size_t)s*4096];

    float accv = 0.f;
    if (t > 0){
      if (tid < 256){
        unsigned long long* slot = mbc + ((size_t)((t-1)&1))*256 + tid;
        unsigned long long vv;
        for(;;){
          vv = __hip_atomic_load(slot, __ATOMIC_RELAXED, __HIP_MEMORY_SCOPE_AGENT);
          if ((unsigned)vv != SENTW && (unsigned)(vv>>32) != SENTW) break;
        }
        // reset for reuse at this parity two steps later (ordering: see header)
        __hip_atomic_store(slot, SENT64, __ATOMIC_RELAXED, __HIP_MEMORY_SCOPE_AGENT);
        float* hb = hsh[t & 1];
        hb[wslot]   = __uint_as_float((unsigned)vv);
        hb[wslot+1] = __uint_as_float((unsigned)(vv>>32));
      }
      __syncthreads();               // staging complete

      const float* hv = hsh[t & 1] + kc*68;
      float p0=0.f,p1=0.f,p2=0.f,p3=0.f;
      #pragma unroll
      for (int j=0;j<16;j++){
        float4 q = *(const float4*)(hv + 4*j);
        p0 = fmaf(wreg[4*j+0], q.x, p0);
        p1 = fmaf(wreg[4*j+1], q.y, p1);
        p2 = fmaf(wreg[4*j+2], q.z, p2);
        p3 = fmaf(wreg[4*j+3], q.w, p3);
      }
      accv = (p0+p1)+(p2+p3);
      accv += __shfl_xor(accv, 1);
      accv += __shfl_xor(accv, 2);
      accv += __shfl_xor(accv, 4);   // lanes with kc==0 hold the full dot
    }
    // per-gate activation (parallel across gate rows)
    float act = 0.f;
    if (kc==0){
      float g = accv + preval;
      act = (gate==2) ? tanh_fast(g) : sigf(g);
    }
    float ai = __shfl(act, base+0);
    float af = __shfl(act, base+8);
    float ag = __shfl(act, base+16);
    float ao = __shfl(act, base+24);
    float h = 0.f;
    if ((lane&31)==0){               // lanes 0,32: units w*16+2wv, w*16+2wv+1
      c = af*c + ai*ag;
      h = ao*tanh_fast(c);
    }
    // broadcast both units' h to all lanes; fan out to 32 private mailboxes
    float hA = __shfl(h, 0);
    float hB = __shfl(h, 32);
    if (lane < 32){
      unsigned long long pv =
          ((unsigned long long)__float_as_uint(hB) << 32) | __float_as_uint(hA);
      unsigned long long* dst =
          mb + ((size_t)(dir*32 + lane)*2 + (t&1))*256 + (w*8 + wv);
      __hip_atomic_store(dst, pv, __ATOMIC_RELEASE, __HIP_MEMORY_SCOPE_AGENT);
    }
    // plain data store for downstream GEMMs (read after kernel completion)
    if ((lane&31)==0){
      out[(size_t)s*1024 + dir*512 + unit] = h;
    }
  }
}

// ---------------- row softmax, in place ----------------
__global__ __launch_bounds__(256) void k_softmax(float* __restrict__ P){
  __shared__ float redm[4], reds[4];
  const int i = blockIdx.x, tid = threadIdx.x;
  float4 v = *(float4*)&P[(size_t)i*1024 + tid*4];
  float m = fmaxf(fmaxf(v.x,v.y), fmaxf(v.z,v.w));
  #pragma unroll
  for (int o=32;o;o>>=1) m = fmaxf(m, __shfl_xor(m,o));
  if ((tid&63)==0) redm[tid>>6] = m;
  __syncthreads();
  m = fmaxf(fmaxf(redm[0],redm[1]), fmaxf(redm[2],redm[3]));
  v.x = expf(v.x-m); v.y = expf(v.y-m); v.z = expf(v.z-m); v.w = expf(v.w-m);
  float su = v.x+v.y+v.z+v.w;
  #pragma unroll
  for (int o=32;o;o>>=1) su += __shfl_xor(su,o);
  if ((tid&63)==0) reds[tid>>6] = su;
  __syncthreads();
  su = reds[0]+reds[1]+reds[2]+reds[3];
  float inv = 1.f/su;
  v.x*=inv; v.y*=inv; v.z*=inv; v.w*=inv;
  *(float4*)&P[(size_t)i*1024 + tid*4] = v;
}

extern "C" void kernel_launch(void* const* d_in, const int* in_sizes, int n_in,
                              void* d_out, int out_size, void* d_ws, size_t ws_size,
                              hipStream_t stream)
{
  const int*   x    = (const int*)d_in[0];
  const int*   xp   = (const int*)d_in[1];
  const float* we   = (const float*)d_in[2];
  const float* pe   = (const float*)d_in[3];
  const float* Wih  = (const float*)d_in[4];
  const float* Whh  = (const float*)d_in[5];
  const float* bl   = (const float*)d_in[6];
  const float* Wh   = (const float*)d_in[7];
  const float* bh   = (const float*)d_in[8];
  const float* Wd   = (const float*)d_in[9];
  const float* bd   = (const float*)d_in[10];
  const float* Wbi  = (const float*)d_in[11];
  const float* bbi  = (const float*)d_in[12];
  float* outp = (float*)d_out;

  char* ws = (char*)d_ws;
  float* X0   = (float*)(ws);                   // [0,4M)
  float* pre  = (float*)(ws + ((size_t)4<<20)); // [4M,20M)
  float* out0 = (float*)(ws + ((size_t)20<<20));// [20M,24M)
  float* out1 = (float*)(ws + ((size_t)24<<20));// [24M,28M)
  float* head = (float*)(ws);                   // reuse [0,4M)
  float* dep  = (float*)(ws + ((size_t)4<<20)); // reuse [4M,8M)
  float* Ubuf = (float*)(ws + ((size_t)8<<20)); // reuse [8M,12M)

  // mailboxes live in d_out (dead during scans; fully overwritten afterwards).
  // one region per layer (512KB total) -> no cross-layer stale-parity hazard.
  unsigned long long* mb0 = (unsigned long long*)d_out;
  unsigned long long* mb1 = mb0 + (256*1024/8);
  hipMemsetAsync(d_out, 0x7F, 512*1024, stream);

  dim3 blk(256);
  k_embed<<<1024, blk, 0, stream>>>(x, xp, we, pe, X0);

  k_gemm_abT<<<dim3(32,8), blk, 0, stream>>>(X0, Wih, pre, 1024, 4096, 1024, bl, nullptr);
  k_lstm_scan<<<64, dim3(512), 0, stream>>>(pre, Whh, out0, mb0);

  k_gemm_abT<<<dim3(32,8), blk, 0, stream>>>(out0, Wih + (size_t)4096*1024, pre,
                                             1024, 4096, 1024, bl + 4096, nullptr);
  k_lstm_scan<<<64, dim3(512), 0, stream>>>(pre, Whh + (size_t)2*2048*512, out1, mb1);

  k_gemm_hd <<<dim3(16,8), blk, 0, stream>>>(out1, Wh, bh, head, Wd, bd, dep);
  k_gemm_abT<<<dim3(8,8), blk, 0, stream>>>(dep,  Wbi, Ubuf,1024, 1024, 1024, nullptr, nullptr);
  k_gemm_abT<<<dim3(8,8), blk, 0, stream>>>(head, Ubuf, outp,1024, 1024, 1024, nullptr, bbi);

  k_softmax<<<1024, blk, 0, stream>>>(outp);
}